// Round 6
// baseline (364.961 us; speedup 1.0000x reference)
//
#include <hip/hip_runtime.h>

static constexpr int NB = 128;    // batches
static constexpr int NN = 512;    // agents (rows)
static constexpr int NM = 512;    // tasks (cols)
static constexpr int STRIPS = 16; // workgroups per batch (2048 wgs total)
static constexpr int NTHREADS = 256;
static constexpr int NITER = 5;
static constexpr int PSZ = NB * NM * STRIPS; // floats per partial buffer (4 MB)

// Non-cooperative 6-launch schedule; stream order replaces grid.sync.
//   K0: X = msk*exp(rowsoftmax(exp(logits)));  zero-fill invalid; col partials
//   K1 x4: colsum gather; Ez=msk*exp(Y/colsum); Y'=msk*exp(Ez/rowsum); partials
//   K2: out = Y/colsum
// 2048 wgs (8/CU queued, 4 resident): heavy-batch strips get backfilled by the
// scheduler -> makespan ~ mean work, not max (round-5's 1024-wg launch had every
// wg resident from t=0, so one heavy CU set a ~2x makespan).
// blockIdx = s*128 + b -> XCD = b%8 for all strips of batch b (partials L2-local).
// Row ownership: 64 streams, r = (4s+wv) + 64*i  -> per-wave work ~ na/64.

__device__ __forceinline__ float wave_sum(float v) {
#pragma unroll
    for (int off = 32; off >= 1; off >>= 1) v += __shfl_xor(v, off, 64);
    return v;
}

__global__ __launch_bounds__(NTHREADS, 4)
void k0_init(const float* __restrict__ logits, const int* __restrict__ nfree,
             const int* __restrict__ ntask, float* __restrict__ X,
             float* __restrict__ part0)
{
    const int b = blockIdx.x & (NB - 1);
    const int s = blockIdx.x >> 7;
    const int na = nfree[b], nt = ntask[b];
    const int tid = threadIdx.x, wv = tid >> 6, lane = tid & 63;
    float* __restrict__ Xb       = X + (size_t)b * NN * NM;
    const float* __restrict__ Lb = logits + (size_t)b * NN * NM;

    __shared__ __align__(16) float red[4][NM];

    const int m0 = lane * 4, m1 = 256 + lane * 4;
    const bool a0 = (m0 < nt), a1 = (m1 < nt);
    float msk[8];
#pragma unroll
    for (int k = 0; k < 8; ++k)
        msk[k] = (((k < 4) ? m0 + k : m1 + k - 4) < nt) ? 1.f : 0.f;

    const int rstart = 4 * s + wv; // stream id in [0,64)
    float ca[8];
#pragma unroll
    for (int k = 0; k < 8; ++k) ca[k] = 0.f;

    int r = rstart;
    for (; r < na; r += 64) {
        float e[8];
#pragma unroll
        for (int k = 0; k < 8; ++k) e[k] = 0.f;
        if (a0) {
            const float4 x = *(const float4*)(Lb + (size_t)r * NM + m0);
            e[0] = msk[0] * __expf(x.x); e[1] = msk[1] * __expf(x.y);
            e[2] = msk[2] * __expf(x.z); e[3] = msk[3] * __expf(x.w);
        }
        if (a1) {
            const float4 x = *(const float4*)(Lb + (size_t)r * NM + m1);
            e[4] = msk[4] * __expf(x.x); e[5] = msk[5] * __expf(x.y);
            e[6] = msk[6] * __expf(x.z); e[7] = msk[7] * __expf(x.w);
        }
        const float sum = wave_sum(((e[0] + e[1]) + (e[2] + e[3])) +
                                   ((e[4] + e[5]) + (e[6] + e[7])));
        const float invr = 1.0f / sum; // >0 whenever a0|a1
        float4 o0 = make_float4(0.f, 0.f, 0.f, 0.f), o1 = o0;
        if (a0) {
            o0 = make_float4(msk[0] * __expf(e[0] * invr), msk[1] * __expf(e[1] * invr),
                             msk[2] * __expf(e[2] * invr), msk[3] * __expf(e[3] * invr));
            ca[0] += o0.x; ca[1] += o0.y; ca[2] += o0.z; ca[3] += o0.w;
        }
        if (a1) {
            o1 = make_float4(msk[4] * __expf(e[4] * invr), msk[5] * __expf(e[5] * invr),
                             msk[6] * __expf(e[6] * invr), msk[7] * __expf(e[7] * invr));
            ca[4] += o1.x; ca[5] += o1.y; ca[6] += o1.z; ca[7] += o1.w;
        }
        *(float4*)(Xb + (size_t)r * NM + m0) = o0;
        *(float4*)(Xb + (size_t)r * NM + m1) = o1;
    }
    const float4 z4 = make_float4(0.f, 0.f, 0.f, 0.f);
    for (; r < NN; r += 64) { // zero-fill invalid rows once
        *(float4*)(Xb + (size_t)r * NM + m0) = z4;
        *(float4*)(Xb + (size_t)r * NM + m1) = z4;
    }

    *(float4*)&red[wv][m0] = make_float4(ca[0], ca[1], ca[2], ca[3]);
    *(float4*)&red[wv][m1] = make_float4(ca[4], ca[5], ca[6], ca[7]);
    __syncthreads();
    {
        float* pb = part0 + (size_t)b * NM * STRIPS;
        const int c = tid * 2;
        pb[(size_t)c * STRIPS + s]       = (red[0][c] + red[1][c]) + (red[2][c] + red[3][c]);
        pb[(size_t)(c + 1) * STRIPS + s] = (red[0][c + 1] + red[1][c + 1]) + (red[2][c + 1] + red[3][c + 1]);
    }
}

__global__ __launch_bounds__(NTHREADS, 4)
void k1_cr(const int* __restrict__ nfree, const int* __restrict__ ntask,
           float* __restrict__ X, const float* __restrict__ ps,
           float* __restrict__ pd)
{
    const int b = blockIdx.x & (NB - 1);
    const int s = blockIdx.x >> 7;
    const int na = nfree[b], nt = ntask[b];
    const int tid = threadIdx.x, wv = tid >> 6, lane = tid & 63;
    float* __restrict__ Xb = X + (size_t)b * NN * NM;

    __shared__ __align__(16) float red[4][NM];
    __shared__ __align__(16) float csh[NM];

    const float* psb = ps + (size_t)b * NM * STRIPS;
    { // gather column sums from the 16 strip partials (same-XCD L2)
        const int c = tid * 2;
        const float4* p0 = (const float4*)(psb + (size_t)c * STRIPS);
        float4 u = p0[0], v = p0[1], w = p0[2], x = p0[3];
        csh[c] = (((u.x + u.y) + (u.z + u.w)) + ((v.x + v.y) + (v.z + v.w)))
               + (((w.x + w.y) + (w.z + w.w)) + ((x.x + x.y) + (x.z + x.w)));
        const float4* p1 = (const float4*)(psb + (size_t)(c + 1) * STRIPS);
        u = p1[0]; v = p1[1]; w = p1[2]; x = p1[3];
        csh[c + 1] = (((u.x + u.y) + (u.z + u.w)) + ((v.x + v.y) + (v.z + v.w)))
                   + (((w.x + w.y) + (w.z + w.w)) + ((x.x + x.y) + (x.z + x.w)));
    }
    __syncthreads();

    const int m0 = lane * 4, m1 = 256 + lane * 4;
    const bool a0 = (m0 < nt), a1 = (m1 < nt);
    float msk[8], inv[8];
#pragma unroll
    for (int k = 0; k < 8; ++k) {
        const int m = (k < 4) ? m0 + k : m1 + k - 4;
        msk[k] = (m < nt) ? 1.f : 0.f;
        inv[k] = (m < nt) ? 1.0f / csh[m] : 0.f;
    }
    const int rstart = 4 * s + wv;
    float cn[8];
#pragma unroll
    for (int k = 0; k < 8; ++k) cn[k] = 0.f;

    for (int r = rstart; r < na; r += 64) {
        float ez[8];
#pragma unroll
        for (int k = 0; k < 8; ++k) ez[k] = 0.f;
        if (a0) {
            const float4 y = *(const float4*)(Xb + (size_t)r * NM + m0);
            ez[0] = msk[0] * __expf(y.x * inv[0]); ez[1] = msk[1] * __expf(y.y * inv[1]);
            ez[2] = msk[2] * __expf(y.z * inv[2]); ez[3] = msk[3] * __expf(y.w * inv[3]);
        }
        if (a1) {
            const float4 y = *(const float4*)(Xb + (size_t)r * NM + m1);
            ez[4] = msk[4] * __expf(y.x * inv[4]); ez[5] = msk[5] * __expf(y.y * inv[5]);
            ez[6] = msk[6] * __expf(y.z * inv[6]); ez[7] = msk[7] * __expf(y.w * inv[7]);
        }
        const float sum = wave_sum(((ez[0] + ez[1]) + (ez[2] + ez[3])) +
                                   ((ez[4] + ez[5]) + (ez[6] + ez[7])));
        const float invr = 1.0f / sum;
        if (a0) {
            const float4 o = make_float4(
                msk[0] * __expf(ez[0] * invr), msk[1] * __expf(ez[1] * invr),
                msk[2] * __expf(ez[2] * invr), msk[3] * __expf(ez[3] * invr));
            *(float4*)(Xb + (size_t)r * NM + m0) = o;
            cn[0] += o.x; cn[1] += o.y; cn[2] += o.z; cn[3] += o.w;
        }
        if (a1) {
            const float4 o = make_float4(
                msk[4] * __expf(ez[4] * invr), msk[5] * __expf(ez[5] * invr),
                msk[6] * __expf(ez[6] * invr), msk[7] * __expf(ez[7] * invr));
            *(float4*)(Xb + (size_t)r * NM + m1) = o;
            cn[4] += o.x; cn[5] += o.y; cn[6] += o.z; cn[7] += o.w;
        }
    }

    *(float4*)&red[wv][m0] = make_float4(cn[0], cn[1], cn[2], cn[3]);
    *(float4*)&red[wv][m1] = make_float4(cn[4], cn[5], cn[6], cn[7]);
    __syncthreads();
    {
        float* pdb = pd + (size_t)b * NM * STRIPS;
        const int c = tid * 2;
        pdb[(size_t)c * STRIPS + s]       = (red[0][c] + red[1][c]) + (red[2][c] + red[3][c]);
        pdb[(size_t)(c + 1) * STRIPS + s] = (red[0][c + 1] + red[1][c + 1]) + (red[2][c + 1] + red[3][c + 1]);
    }
}

__global__ __launch_bounds__(NTHREADS, 4)
void k2_fin(const int* __restrict__ nfree, const int* __restrict__ ntask,
            float* __restrict__ X, const float* __restrict__ ps)
{
    const int b = blockIdx.x & (NB - 1);
    const int s = blockIdx.x >> 7;
    const int na = nfree[b], nt = ntask[b];
    const int tid = threadIdx.x, wv = tid >> 6, lane = tid & 63;
    float* __restrict__ Xb = X + (size_t)b * NN * NM;

    __shared__ __align__(16) float csh[NM];
    const float* psb = ps + (size_t)b * NM * STRIPS;
    {
        const int c = tid * 2;
        const float4* p0 = (const float4*)(psb + (size_t)c * STRIPS);
        float4 u = p0[0], v = p0[1], w = p0[2], x = p0[3];
        csh[c] = (((u.x + u.y) + (u.z + u.w)) + ((v.x + v.y) + (v.z + v.w)))
               + (((w.x + w.y) + (w.z + w.w)) + ((x.x + x.y) + (x.z + x.w)));
        const float4* p1 = (const float4*)(psb + (size_t)(c + 1) * STRIPS);
        u = p1[0]; v = p1[1]; w = p1[2]; x = p1[3];
        csh[c + 1] = (((u.x + u.y) + (u.z + u.w)) + ((v.x + v.y) + (v.z + v.w)))
                   + (((w.x + w.y) + (w.z + w.w)) + ((x.x + x.y) + (x.z + x.w)));
    }
    __syncthreads();

    const int m0 = lane * 4, m1 = 256 + lane * 4;
    const bool a0 = (m0 < nt), a1 = (m1 < nt);
    float inv[8];
#pragma unroll
    for (int k = 0; k < 8; ++k) {
        const int m = (k < 4) ? m0 + k : m1 + k - 4;
        inv[k] = (m < nt) ? 1.0f / csh[m] : 0.f;
    }
    const int rstart = 4 * s + wv;
    for (int r = rstart; r < na; r += 64) {
        if (a0) {
            const float4 y = *(const float4*)(Xb + (size_t)r * NM + m0);
            *(float4*)(Xb + (size_t)r * NM + m0) =
                make_float4(y.x * inv[0], y.y * inv[1], y.z * inv[2], y.w * inv[3]);
        }
        if (a1) {
            const float4 y = *(const float4*)(Xb + (size_t)r * NM + m1);
            *(float4*)(Xb + (size_t)r * NM + m1) =
                make_float4(y.x * inv[4], y.y * inv[5], y.z * inv[6], y.w * inv[7]);
        }
    }
}

extern "C" void kernel_launch(void* const* d_in, const int* in_sizes, int n_in,
                              void* d_out, int out_size, void* d_ws, size_t ws_size,
                              hipStream_t stream)
{
    (void)in_sizes; (void)n_in; (void)out_size; (void)ws_size;
    const float* logits = (const float*)d_in[0];
    const int* nfree    = (const int*)d_in[1];
    const int* ntask    = (const int*)d_in[2];
    float* X  = (float*)d_out;
    float* p0 = (float*)d_ws;       // [NB][NM][STRIPS] partial colsums, buffer 0
    float* p1 = p0 + PSZ;           // buffer 1 (total 8 MB of ws)

    const dim3 grid(NB * STRIPS), block(NTHREADS);
    hipLaunchKernelGGL(k0_init, grid, block, 0, stream, logits, nfree, ntask, X, p0);
    const float* src = p0;
    float* dst = p1;
    for (int it = 0; it < NITER - 1; ++it) {
        hipLaunchKernelGGL(k1_cr, grid, block, 0, stream, nfree, ntask, X, src, dst);
        const float* t = src; src = dst; dst = (float*)t;
    }
    hipLaunchKernelGGL(k2_fin, grid, block, 0, stream, nfree, ntask, X, src);
}

// Round 7
// 349.518 us; speedup vs baseline: 1.0442x; 1.0442x over previous
//
#include <hip/hip_runtime.h>
#include <hip/hip_cooperative_groups.h>

namespace cg = cooperative_groups;

static constexpr int NB = 128;   // batches
static constexpr int NN = 512;   // agents (rows)
static constexpr int NM = 512;   // tasks (cols)
static constexpr int STRIPS = 8; // workgroups per batch (1024 wgs total)
static constexpr int NTHREADS = 256;
static constexpr int NITER = 5;
static constexpr int PSZ = NB * NM * STRIPS; // floats per partial buffer (2 MB)

// Primary: ONE cooperative kernel, phases separated by grid.sync() — removes the
// 5 inter-kernel launch bubbles that dominated rounds 5/6 (365 us vs ~140 us
// traffic floor). Geometry = round-1-proven 1024 wgs x 256 thr, launch_bounds(256,4).
// Safety: runtime occupancy precheck + error-checked coop launch, falling back to
// the round-5-proven 6-launch path (rounds 2/4 failed by silent coop rejection).
// blockIdx = s*128 + b -> XCD = b%8 for all strips of batch b (partials L2-local).
// Row ownership: 64 streams r = (8wv+s) mod 64 -> per-wave work ~ na/32 balanced.

__device__ __forceinline__ float wave_sum(float v) {
#pragma unroll
    for (int off = 32; off >= 1; off >>= 1) v += __shfl_xor(v, off, 64);
    return v;
}

// ---------------- phase bodies (identical math to the passing round-5 kernels) ----------------

__device__ __forceinline__ void body_init(
    const float* __restrict__ Lb, float* __restrict__ Xb, float* __restrict__ pb,
    int s, int na, int nt, int tid, int wv, int lane, float (&red)[4][NM])
{
    const int m0 = lane * 4, m1 = 256 + lane * 4;
    const bool a0 = (m0 < nt), a1 = (m1 < nt);
    float msk[8];
#pragma unroll
    for (int k = 0; k < 8; ++k)
        msk[k] = (((k < 4) ? m0 + k : m1 + k - 4) < nt) ? 1.f : 0.f;

    const int rstart = s + 8 * wv;
    float ca[8];
#pragma unroll
    for (int k = 0; k < 8; ++k) ca[k] = 0.f;

    int r = rstart;
    for (; r < na; r += 32) {
        float e[8];
#pragma unroll
        for (int k = 0; k < 8; ++k) e[k] = 0.f;
        if (a0) {
            const float4 x = *(const float4*)(Lb + (size_t)r * NM + m0);
            e[0] = msk[0] * __expf(x.x); e[1] = msk[1] * __expf(x.y);
            e[2] = msk[2] * __expf(x.z); e[3] = msk[3] * __expf(x.w);
        }
        if (a1) {
            const float4 x = *(const float4*)(Lb + (size_t)r * NM + m1);
            e[4] = msk[4] * __expf(x.x); e[5] = msk[5] * __expf(x.y);
            e[6] = msk[6] * __expf(x.z); e[7] = msk[7] * __expf(x.w);
        }
        const float sum = wave_sum(((e[0] + e[1]) + (e[2] + e[3])) +
                                   ((e[4] + e[5]) + (e[6] + e[7])));
        const float invr = 1.0f / sum;
        float4 o0 = make_float4(0.f, 0.f, 0.f, 0.f), o1 = o0;
        if (a0) {
            o0 = make_float4(msk[0] * __expf(e[0] * invr), msk[1] * __expf(e[1] * invr),
                             msk[2] * __expf(e[2] * invr), msk[3] * __expf(e[3] * invr));
            ca[0] += o0.x; ca[1] += o0.y; ca[2] += o0.z; ca[3] += o0.w;
        }
        if (a1) {
            o1 = make_float4(msk[4] * __expf(e[4] * invr), msk[5] * __expf(e[5] * invr),
                             msk[6] * __expf(e[6] * invr), msk[7] * __expf(e[7] * invr));
            ca[4] += o1.x; ca[5] += o1.y; ca[6] += o1.z; ca[7] += o1.w;
        }
        *(float4*)(Xb + (size_t)r * NM + m0) = o0;
        *(float4*)(Xb + (size_t)r * NM + m1) = o1;
    }
    const float4 z4 = make_float4(0.f, 0.f, 0.f, 0.f);
    for (; r < NN; r += 32) {
        *(float4*)(Xb + (size_t)r * NM + m0) = z4;
        *(float4*)(Xb + (size_t)r * NM + m1) = z4;
    }

    *(float4*)&red[wv][m0] = make_float4(ca[0], ca[1], ca[2], ca[3]);
    *(float4*)&red[wv][m1] = make_float4(ca[4], ca[5], ca[6], ca[7]);
    __syncthreads();
    {
        const int c = tid * 2;
        pb[(size_t)c * STRIPS + s]       = (red[0][c] + red[1][c]) + (red[2][c] + red[3][c]);
        pb[(size_t)(c + 1) * STRIPS + s] = (red[0][c + 1] + red[1][c + 1]) + (red[2][c + 1] + red[3][c + 1]);
    }
}

__device__ __forceinline__ void gather_colsums(
    const float* __restrict__ psb, int tid, float (&csh)[NM])
{
    const int c = tid * 2;
    const float4* p0 = (const float4*)(psb + (size_t)c * STRIPS);
    float4 u = p0[0], v = p0[1];
    csh[c] = ((u.x + u.y) + (u.z + u.w)) + ((v.x + v.y) + (v.z + v.w));
    const float4* p1 = (const float4*)(psb + (size_t)(c + 1) * STRIPS);
    u = p1[0]; v = p1[1];
    csh[c + 1] = ((u.x + u.y) + (u.z + u.w)) + ((v.x + v.y) + (v.z + v.w));
}

__device__ __forceinline__ void body_cr(
    float* __restrict__ Xb, const float* __restrict__ psb, float* __restrict__ pdb,
    int s, int na, int nt, int tid, int wv, int lane,
    float (&red)[4][NM], float (&csh)[NM])
{
    gather_colsums(psb, tid, csh);
    __syncthreads();

    const int m0 = lane * 4, m1 = 256 + lane * 4;
    const bool a0 = (m0 < nt), a1 = (m1 < nt);
    float msk[8], inv[8];
#pragma unroll
    for (int k = 0; k < 8; ++k) {
        const int m = (k < 4) ? m0 + k : m1 + k - 4;
        msk[k] = (m < nt) ? 1.f : 0.f;
        inv[k] = (m < nt) ? 1.0f / csh[m] : 0.f;
    }
    const int rstart = s + 8 * wv;
    float cn[8];
#pragma unroll
    for (int k = 0; k < 8; ++k) cn[k] = 0.f;

    for (int r = rstart; r < na; r += 32) {
        float ez[8];
#pragma unroll
        for (int k = 0; k < 8; ++k) ez[k] = 0.f;
        if (a0) {
            const float4 y = *(const float4*)(Xb + (size_t)r * NM + m0);
            ez[0] = msk[0] * __expf(y.x * inv[0]); ez[1] = msk[1] * __expf(y.y * inv[1]);
            ez[2] = msk[2] * __expf(y.z * inv[2]); ez[3] = msk[3] * __expf(y.w * inv[3]);
        }
        if (a1) {
            const float4 y = *(const float4*)(Xb + (size_t)r * NM + m1);
            ez[4] = msk[4] * __expf(y.x * inv[4]); ez[5] = msk[5] * __expf(y.y * inv[5]);
            ez[6] = msk[6] * __expf(y.z * inv[6]); ez[7] = msk[7] * __expf(y.w * inv[7]);
        }
        const float sum = wave_sum(((ez[0] + ez[1]) + (ez[2] + ez[3])) +
                                   ((ez[4] + ez[5]) + (ez[6] + ez[7])));
        const float invr = 1.0f / sum;
        if (a0) {
            const float4 o = make_float4(
                msk[0] * __expf(ez[0] * invr), msk[1] * __expf(ez[1] * invr),
                msk[2] * __expf(ez[2] * invr), msk[3] * __expf(ez[3] * invr));
            *(float4*)(Xb + (size_t)r * NM + m0) = o;
            cn[0] += o.x; cn[1] += o.y; cn[2] += o.z; cn[3] += o.w;
        }
        if (a1) {
            const float4 o = make_float4(
                msk[4] * __expf(ez[4] * invr), msk[5] * __expf(ez[5] * invr),
                msk[6] * __expf(ez[6] * invr), msk[7] * __expf(ez[7] * invr));
            *(float4*)(Xb + (size_t)r * NM + m1) = o;
            cn[4] += o.x; cn[5] += o.y; cn[6] += o.z; cn[7] += o.w;
        }
    }

    *(float4*)&red[wv][m0] = make_float4(cn[0], cn[1], cn[2], cn[3]);
    *(float4*)&red[wv][m1] = make_float4(cn[4], cn[5], cn[6], cn[7]);
    __syncthreads();
    {
        const int c = tid * 2;
        pdb[(size_t)c * STRIPS + s]       = (red[0][c] + red[1][c]) + (red[2][c] + red[3][c]);
        pdb[(size_t)(c + 1) * STRIPS + s] = (red[0][c + 1] + red[1][c + 1]) + (red[2][c + 1] + red[3][c + 1]);
    }
}

__device__ __forceinline__ void body_fin(
    float* __restrict__ Xb, const float* __restrict__ psb,
    int s, int na, int nt, int tid, int wv, int lane, float (&csh)[NM])
{
    gather_colsums(psb, tid, csh);
    __syncthreads();

    const int m0 = lane * 4, m1 = 256 + lane * 4;
    const bool a0 = (m0 < nt), a1 = (m1 < nt);
    float inv[8];
#pragma unroll
    for (int k = 0; k < 8; ++k) {
        const int m = (k < 4) ? m0 + k : m1 + k - 4;
        inv[k] = (m < nt) ? 1.0f / csh[m] : 0.f;
    }
    const int rstart = s + 8 * wv;
    for (int r = rstart; r < na; r += 32) {
        if (a0) {
            const float4 y = *(const float4*)(Xb + (size_t)r * NM + m0);
            *(float4*)(Xb + (size_t)r * NM + m0) =
                make_float4(y.x * inv[0], y.y * inv[1], y.z * inv[2], y.w * inv[3]);
        }
        if (a1) {
            const float4 y = *(const float4*)(Xb + (size_t)r * NM + m1);
            *(float4*)(Xb + (size_t)r * NM + m1) =
                make_float4(y.x * inv[4], y.y * inv[5], y.z * inv[6], y.w * inv[7]);
        }
    }
}

// ---------------- primary: single cooperative kernel ----------------

__global__ __launch_bounds__(NTHREADS, 4)
void gs_coop(const float* __restrict__ logits, const int* __restrict__ nfree,
             const int* __restrict__ ntask, float* __restrict__ X,
             float* __restrict__ part)
{
    cg::grid_group grid = cg::this_grid();
    const int b = blockIdx.x & (NB - 1);
    const int s = blockIdx.x >> 7;
    const int na = nfree[b], nt = ntask[b];
    const int tid = threadIdx.x, wv = tid >> 6, lane = tid & 63;

    float* __restrict__ Xb       = X + (size_t)b * NN * NM;
    const float* __restrict__ Lb = logits + (size_t)b * NN * NM;
    float* const pbase = part + (size_t)b * NM * STRIPS;

    __shared__ __align__(16) float red[4][NM];
    __shared__ __align__(16) float csh[NM];

    body_init(Lb, Xb, pbase, s, na, nt, tid, wv, lane, red);
    grid.sync();

    for (int it = 0; it < NITER - 1; ++it) {
        const float* psb = pbase + ((it & 1) ? PSZ : 0);
        float* pdb       = pbase + ((it & 1) ? 0 : PSZ);
        body_cr(Xb, psb, pdb, s, na, nt, tid, wv, lane, red, csh);
        grid.sync();
    }
    body_fin(Xb, pbase, s, na, nt, tid, wv, lane, csh); // after 4 swaps src = buffer 0
}

// ---------------- fallback: round-5-proven 6-launch sequence ----------------

__global__ __launch_bounds__(NTHREADS, 4)
void k0_init(const float* __restrict__ logits, const int* __restrict__ nfree,
             const int* __restrict__ ntask, float* __restrict__ X,
             float* __restrict__ part0)
{
    const int b = blockIdx.x & (NB - 1), s = blockIdx.x >> 7;
    const int tid = threadIdx.x, wv = tid >> 6, lane = tid & 63;
    __shared__ __align__(16) float red[4][NM];
    body_init(logits + (size_t)b * NN * NM, X + (size_t)b * NN * NM,
              part0 + (size_t)b * NM * STRIPS, s, nfree[b], ntask[b], tid, wv, lane, red);
}

__global__ __launch_bounds__(NTHREADS, 4)
void k1_cr(const int* __restrict__ nfree, const int* __restrict__ ntask,
           float* __restrict__ X, const float* __restrict__ ps, float* __restrict__ pd)
{
    const int b = blockIdx.x & (NB - 1), s = blockIdx.x >> 7;
    const int tid = threadIdx.x, wv = tid >> 6, lane = tid & 63;
    __shared__ __align__(16) float red[4][NM];
    __shared__ __align__(16) float csh[NM];
    body_cr(X + (size_t)b * NN * NM, ps + (size_t)b * NM * STRIPS,
            pd + (size_t)b * NM * STRIPS, s, nfree[b], ntask[b], tid, wv, lane, red, csh);
}

__global__ __launch_bounds__(NTHREADS, 4)
void k2_fin(const int* __restrict__ nfree, const int* __restrict__ ntask,
            float* __restrict__ X, const float* __restrict__ ps)
{
    const int b = blockIdx.x & (NB - 1), s = blockIdx.x >> 7;
    const int tid = threadIdx.x, wv = tid >> 6, lane = tid & 63;
    __shared__ __align__(16) float csh[NM];
    body_fin(X + (size_t)b * NN * NM, ps + (size_t)b * NM * STRIPS,
             s, nfree[b], ntask[b], tid, wv, lane, csh);
}

extern "C" void kernel_launch(void* const* d_in, const int* in_sizes, int n_in,
                              void* d_out, int out_size, void* d_ws, size_t ws_size,
                              hipStream_t stream)
{
    (void)in_sizes; (void)n_in; (void)out_size; (void)ws_size;
    const float* logits = (const float*)d_in[0];
    const int* nfree    = (const int*)d_in[1];
    const int* ntask    = (const int*)d_in[2];
    float* X    = (float*)d_out;
    float* part = (float*)d_ws; // 2 x PSZ floats = 4 MB (buffer1 at part+PSZ)

    // Deterministic, capture-safe host-side co-residency check (same result every
    // call): can 1024 wgs of gs_coop be simultaneously resident?
    bool coop_ok = false;
    {
        int dev = 0;
        if (hipGetDevice(&dev) == hipSuccess) {
            int num_cu = 0, max_blk = 0;
            if (hipDeviceGetAttribute(&num_cu, hipDeviceAttributeMultiprocessorCount, dev) == hipSuccess &&
                hipOccupancyMaxActiveBlocksPerMultiprocessor(&max_blk, gs_coop, NTHREADS, 0) == hipSuccess)
                coop_ok = ((long)max_blk * num_cu >= NB * STRIPS);
        }
    }

    if (coop_ok) {
        void* args[] = {(void*)&logits, (void*)&nfree, (void*)&ntask,
                        (void*)&X, (void*)&part};
        coop_ok = (hipSuccess == hipLaunchCooperativeKernel(
                       (const void*)gs_coop, dim3(NB * STRIPS), dim3(NTHREADS),
                       args, 0, stream));
    }
    if (!coop_ok) { // proven round-5 path
        const dim3 grid(NB * STRIPS), block(NTHREADS);
        hipLaunchKernelGGL(k0_init, grid, block, 0, stream, logits, nfree, ntask, X, part);
        const float* src = part;
        float* dst = part + PSZ;
        for (int it = 0; it < NITER - 1; ++it) {
            hipLaunchKernelGGL(k1_cr, grid, block, 0, stream, nfree, ntask, X, src, dst);
            const float* t = src; src = dst; dst = (float*)t;
        }
        hipLaunchKernelGGL(k2_fin, grid, block, 0, stream, nfree, ntask, X, src);
    }
}